// Round 5
// baseline (120.503 us; speedup 1.0000x reference)
//
#include <hip/hip_runtime.h>
#include <math.h>

#define LENGTH   8192
#define CHANNELS 512
#define NSTATE   64
#define TCHUNK   64
#define NCHUNK   (LENGTH / TCHUNK)            /* 128 */
#define E_ELEMS  (NCHUNK * NSTATE * CHANNELS) /* 16 MB: E / carry buffer in ws */
#define TSTRIDE  72                           /* ushorts per column in LDS transposed arrays */

// Chunked S4 scan (rescaled state h' = h/Bbar):
//   pass1: E_k = G @ X_k            G[n][s]  = Abar_n^(63-s)
//   pass2: carry[k] = AbarT*carry[k-1] + E[k-1]    (serial, in place, fp32)
//   pass3: Y_k = T @ X_k + P @ Hc_k T[t][s]  = (t>=s) ? K[t-s] : 0,  K[d] = sum_n CB_n Abar_n^d
//                                   P[t][n]  = CB_n Abar_n^(t+1)
// pass1/pass3 GEMMs run on MFMA (bf16) with full hi/lo split:
//   A@B ~= Ah@Bh + Ah@Bl + Al@Bh   (dropped Al@Bl ~ 2^-18 rel -> fp32-grade accuracy)
// MFMA 16x16x32 layouts (measured, m89): A[m=lane&15][k=(lane>>4)*8+j],
//   B[k=(lane>>4)*8+j][n=lane&15], D[row=(lane>>4)*4+reg][col=lane&15].

typedef __attribute__((ext_vector_type(8))) short bf16x8;
typedef __attribute__((ext_vector_type(4))) float f32x4;

static __device__ __forceinline__ unsigned short f2bf(float f) {
    unsigned int u = __float_as_uint(f);
    u += 0x7fff + ((u >> 16) & 1);            // RNE (finite values only)
    return (unsigned short)(u >> 16);
}
static __device__ __forceinline__ float bf2f(unsigned short h) {
    return __uint_as_float(((unsigned int)h) << 16);
}

// ---------------------------------------------------------------------------
// Prep (1 block, 256 threads): G/T/P as bf16 hi+lo, row-major [m][k], fp64 math.
// mats layout (ushort): Gh | Gl | Th | Tl | Ph | Pl, 4096 each.
// ---------------------------------------------------------------------------
__global__ void k_prep(const float* __restrict__ logA, const float* __restrict__ B,
                       const float* __restrict__ C, unsigned short* __restrict__ mats) {
    __shared__ double dl2[64], dCB[64], Kp[256], Kd[64];
    int tid = threadIdx.x;
    if (tid < 64) {
        double A    = -exp((double)logA[tid]);
        double lab  = A * (1.0 / 4096.0);                 // ln(Abar)
        double Bbar = expm1(lab) * (double)B[tid] / A;    // (Abar-1)*B/A
        dl2[tid] = lab;
        dCB[tid] = (double)C[tid] * Bbar;
    }
    __syncthreads();
    {   // K[d] partials: thread (d = tid&63, q = tid>>6) sums 16 states
        int d = tid & 63, q = tid >> 6;
        double s = 0.0;
        for (int i = 0; i < 16; ++i) { int n = q * 16 + i; s += dCB[n] * exp(dl2[n] * (double)d); }
        Kp[q * 64 + d] = s;
    }
    __syncthreads();
    if (tid < 64) Kd[tid] = (Kp[tid] + Kp[64 + tid]) + (Kp[128 + tid] + Kp[192 + tid]);
    __syncthreads();

    unsigned short *Gh = mats,          *Gl = mats + 4096;
    unsigned short *Th = mats + 8192,   *Tl = mats + 12288;
    unsigned short *Ph = mats + 16384,  *Pl = mats + 20480;
    int r = tid >> 2, cb = (tid & 3) * 16;                // row r, 16-col strip
    for (int j = 0; j < 16; ++j) {
        int kk = cb + j;
        double g = exp(dl2[r] * (double)(63 - kk));       // G[r][kk]
        unsigned short h = f2bf((float)g);
        Gh[r * 64 + kk] = h; Gl[r * 64 + kk] = f2bf((float)g - bf2f(h));

        double tv = (r >= kk) ? Kd[r - kk] : 0.0;         // T[r][kk]
        h = f2bf((float)tv);
        Th[r * 64 + kk] = h; Tl[r * 64 + kk] = f2bf((float)tv - bf2f(h));

        double pv = dCB[kk] * exp(dl2[kk] * (double)(r + 1)); // P[r][kk]
        h = f2bf((float)pv);
        Ph[r * 64 + kk] = h; Pl[r * 64 + kk] = f2bf((float)pv - bf2f(h));
    }
}

// Stage a 64x64 fp32 global tile into transposed bf16 hi/lo LDS arrays.
// Thread (c = tid&63, g = tid>>6) handles rows 16g..16g+15 of column c.
static __device__ __forceinline__ void stage_tile(const float* __restrict__ src,
                                                  unsigned short* __restrict__ Dh,
                                                  unsigned short* __restrict__ Dl,
                                                  int tid) {
    int c = tid & 63, g = tid >> 6;
    const float* sp = src + (size_t)(16 * g) * CHANNELS + c;
    float v[16];
    #pragma unroll
    for (int j = 0; j < 16; ++j) v[j] = sp[(size_t)j * CHANNELS];
    bf16x8 h0, h1, l0, l1;
    #pragma unroll
    for (int j = 0; j < 8; ++j) {
        unsigned short a = f2bf(v[j]), b = f2bf(v[8 + j]);
        h0[j] = (short)a; h1[j] = (short)b;
        l0[j] = (short)f2bf(v[j] - bf2f(a));
        l1[j] = (short)f2bf(v[8 + j] - bf2f(b));
    }
    *(bf16x8*)&Dh[c * TSTRIDE + 16 * g]     = h0;
    *(bf16x8*)&Dh[c * TSTRIDE + 16 * g + 8] = h1;
    *(bf16x8*)&Dl[c * TSTRIDE + 16 * g]     = l0;
    *(bf16x8*)&Dl[c * TSTRIDE + 16 * g + 8] = l1;
}

// ---------------------------------------------------------------------------
// Pass 1 (MFMA): E_k = G @ X_k. Block = (chunk k, 64-ch tile); wave = 16 cols.
// ---------------------------------------------------------------------------
__global__ __launch_bounds__(256, 4) void k_pass1(const float* __restrict__ x,
                                                  const unsigned short* __restrict__ mats,
                                                  float* __restrict__ E) {
    __shared__ unsigned short Xh[64 * TSTRIDE], Xl[64 * TSTRIDE];
    int tid = threadIdx.x;
    int k = blockIdx.x >> 3, c0g = (blockIdx.x & 7) * 64;

    stage_tile(x + (size_t)k * TCHUNK * CHANNELS + c0g, Xh, Xl, tid);
    __syncthreads();

    int w = tid >> 6, lane = tid & 63;
    int p = lane & 15, q = lane >> 4;
    const unsigned short *Gh = mats, *Gl = mats + 4096;

    f32x4 acc[4] = {{0.f,0.f,0.f,0.f},{0.f,0.f,0.f,0.f},{0.f,0.f,0.f,0.f},{0.f,0.f,0.f,0.f}};
    #pragma unroll
    for (int ks = 0; ks < 2; ++ks) {
        int bidx = (16 * w + p) * TSTRIDE + 32 * ks + 8 * q;
        bf16x8 bh = *(bf16x8*)&Xh[bidx];
        bf16x8 bl = *(bf16x8*)&Xl[bidx];
        #pragma unroll
        for (int mt = 0; mt < 4; ++mt) {
            int aidx = (16 * mt + p) * 64 + 32 * ks + 8 * q;
            bf16x8 ah = *(const bf16x8*)&Gh[aidx];
            bf16x8 al = *(const bf16x8*)&Gl[aidx];
            acc[mt] = __builtin_amdgcn_mfma_f32_16x16x32_bf16(ah, bh, acc[mt], 0, 0, 0);
            acc[mt] = __builtin_amdgcn_mfma_f32_16x16x32_bf16(ah, bl, acc[mt], 0, 0, 0);
            acc[mt] = __builtin_amdgcn_mfma_f32_16x16x32_bf16(al, bh, acc[mt], 0, 0, 0);
        }
    }
    #pragma unroll
    for (int mt = 0; mt < 4; ++mt) {
        float* Ep = E + ((size_t)k * NSTATE + 16 * mt + 4 * q) * CHANNELS + c0g + 16 * w + p;
        #pragma unroll
        for (int r = 0; r < 4; ++r) Ep[(size_t)r * CHANNELS] = acc[mt][r];
    }
}

// ---------------------------------------------------------------------------
// Pass 2: per (state n, channel c): serial carry scan over chunks, in place,
// group-16 double-buffered fp32. n is block-uniform -> aT scalar.
// ---------------------------------------------------------------------------
#define G2 16
__global__ __launch_bounds__(64, 1) void k_pass2(float* __restrict__ W,
                                                 const float* __restrict__ logA) {
    int gtid = blockIdx.x * 64 + threadIdx.x;
    int c = gtid & (CHANNELS - 1);
    int n = gtid >> 9;
    float A  = -expf(logA[n]);
    float aT = expf(A * (64.0f / 4096.0f));   // Abar^TCHUNK
    float* p = W + (size_t)n * CHANNELS + c;
    const size_t S = (size_t)NSTATE * CHANNELS;

    float e[2][G2];
    #pragma unroll
    for (int j = 0; j < G2; ++j) e[0][j] = p[(size_t)j * S];

    float hc = 0.f;
    #pragma unroll
    for (int k0 = 0; k0 < NCHUNK; k0 += G2) {
        const int cur = (k0 / G2) & 1, nxt = cur ^ 1;
        if (k0 + G2 < NCHUNK) {
            #pragma unroll
            for (int j = 0; j < G2; ++j) e[nxt][j] = p[(size_t)(k0 + G2 + j) * S];
        }
        #pragma unroll
        for (int j = 0; j < G2; ++j) {
            p[(size_t)(k0 + j) * S] = hc;
            hc = fmaf(aT, hc, e[cur][j]);
        }
    }
}

// ---------------------------------------------------------------------------
// Pass 3 (MFMA): Y_k = T @ X_k + P @ Hc_k. Same structure, two B-sources.
// LDS 36 KB -> 4 blocks/CU.
// ---------------------------------------------------------------------------
__global__ __launch_bounds__(256, 4) void k_pass3(const float* __restrict__ x,
                                                  const unsigned short* __restrict__ mats,
                                                  const float* __restrict__ Wc,
                                                  float* __restrict__ y) {
    __shared__ unsigned short Xh[64 * TSTRIDE], Xl[64 * TSTRIDE];
    __shared__ unsigned short Hh[64 * TSTRIDE], Hl[64 * TSTRIDE];
    int tid = threadIdx.x;
    int k = blockIdx.x >> 3, c0g = (blockIdx.x & 7) * 64;

    stage_tile(x  + (size_t)k * TCHUNK * CHANNELS + c0g, Xh, Xl, tid);
    stage_tile(Wc + (size_t)k * NSTATE * CHANNELS + c0g, Hh, Hl, tid);
    __syncthreads();

    int w = tid >> 6, lane = tid & 63;
    int p = lane & 15, q = lane >> 4;
    const unsigned short *Th = mats + 8192,  *Tl = mats + 12288;
    const unsigned short *Ph = mats + 16384, *Pl = mats + 20480;

    f32x4 acc[4] = {{0.f,0.f,0.f,0.f},{0.f,0.f,0.f,0.f},{0.f,0.f,0.f,0.f},{0.f,0.f,0.f,0.f}};
    #pragma unroll
    for (int ks = 0; ks < 2; ++ks) {
        int bidx = (16 * w + p) * TSTRIDE + 32 * ks + 8 * q;
        bf16x8 bxh = *(bf16x8*)&Xh[bidx];
        bf16x8 bxl = *(bf16x8*)&Xl[bidx];
        bf16x8 bhh = *(bf16x8*)&Hh[bidx];
        bf16x8 bhl = *(bf16x8*)&Hl[bidx];
        #pragma unroll
        for (int mt = 0; mt < 4; ++mt) {
            int aidx = (16 * mt + p) * 64 + 32 * ks + 8 * q;
            bf16x8 ath = *(const bf16x8*)&Th[aidx];
            bf16x8 atl = *(const bf16x8*)&Tl[aidx];
            acc[mt] = __builtin_amdgcn_mfma_f32_16x16x32_bf16(ath, bxh, acc[mt], 0, 0, 0);
            acc[mt] = __builtin_amdgcn_mfma_f32_16x16x32_bf16(ath, bxl, acc[mt], 0, 0, 0);
            acc[mt] = __builtin_amdgcn_mfma_f32_16x16x32_bf16(atl, bxh, acc[mt], 0, 0, 0);
            bf16x8 aph = *(const bf16x8*)&Ph[aidx];
            bf16x8 apl = *(const bf16x8*)&Pl[aidx];
            acc[mt] = __builtin_amdgcn_mfma_f32_16x16x32_bf16(aph, bhh, acc[mt], 0, 0, 0);
            acc[mt] = __builtin_amdgcn_mfma_f32_16x16x32_bf16(aph, bhl, acc[mt], 0, 0, 0);
            acc[mt] = __builtin_amdgcn_mfma_f32_16x16x32_bf16(apl, bhh, acc[mt], 0, 0, 0);
        }
    }
    #pragma unroll
    for (int mt = 0; mt < 4; ++mt) {
        float* yp = y + ((size_t)k * TCHUNK + 16 * mt + 4 * q) * CHANNELS + c0g + 16 * w + p;
        #pragma unroll
        for (int r = 0; r < 4; ++r) yp[(size_t)r * CHANNELS] = acc[mt][r];
    }
}

// ---------------------------------------------------------------------------
// Fallback (only if ws is too small): one thread per channel, full scan.
// ---------------------------------------------------------------------------
__global__ __launch_bounds__(256) void k_fallback(const float* __restrict__ x,
                                                  const float* __restrict__ logA,
                                                  const float* __restrict__ B,
                                                  const float* __restrict__ C,
                                                  float* __restrict__ y) {
    int c = blockIdx.x * blockDim.x + threadIdx.x;
    if (c >= CHANNELS) return;
    float Abar[NSTATE], CB[NSTATE], h[NSTATE];
    for (int n = 0; n < NSTATE; ++n) {
        float A    = -expf(logA[n]);
        float ab   = expf(A / 4096.0f);
        float Bbar = expm1f(A / 4096.0f) * B[n] / A;
        Abar[n] = ab; CB[n] = C[n] * Bbar; h[n] = 0.f;
    }
    for (int t = 0; t < LENGTH; ++t) {
        float xv = x[(size_t)t * CHANNELS + c];
        float acc = 0.f;
        for (int n = 0; n < NSTATE; ++n) {
            h[n] = fmaf(Abar[n], h[n], xv);
            acc  = fmaf(CB[n], h[n], acc);
        }
        y[(size_t)t * CHANNELS + c] = acc;
    }
}

extern "C" void kernel_launch(void* const* d_in, const int* in_sizes, int n_in,
                              void* d_out, int out_size, void* d_ws, size_t ws_size,
                              hipStream_t stream) {
    const float* x    = (const float*)d_in[0];
    const float* logA = (const float*)d_in[1];
    const float* B    = (const float*)d_in[2];
    const float* C    = (const float*)d_in[3];
    float* yout = (float*)d_out;

    size_t need = (size_t)E_ELEMS * sizeof(float) + 6 * 4096 * sizeof(unsigned short);
    if (ws_size < need) {
        k_fallback<<<(CHANNELS + 255) / 256, 256, 0, stream>>>(x, logA, B, C, yout);
        return;
    }
    float*          W    = (float*)d_ws;                 // E / carry buffer, 16 MB
    unsigned short* mats = (unsigned short*)(W + E_ELEMS);

    k_prep <<<1, 256, 0, stream>>>(logA, B, C, mats);
    k_pass1<<<NCHUNK * 8, 256, 0, stream>>>(x, mats, W);
    k_pass2<<<(NSTATE * CHANNELS) / 64, 64, 0, stream>>>(W, logA);
    k_pass3<<<NCHUNK * 8, 256, 0, stream>>>(x, mats, W, yout);
}

// Round 6
// 109.182 us; speedup vs baseline: 1.1037x; 1.1037x over previous
//
#include <hip/hip_runtime.h>
#include <math.h>

#define LENGTH   8192
#define CHANNELS 512
#define NSTATE   64
#define TCHUNK   64
#define NCHUNK   (LENGTH / TCHUNK)            /* 128 */
#define E_ELEMS  (NCHUNK * NSTATE * CHANNELS) /* 16 MB: E / carry buffer in ws */
#define LOG2E    1.4426950408889634f
#define DT       (1.0f / 4096.0f)

// Chunked S4 scan (rescaled state h' = h/Bbar):  h'_t = Abar*h'_{t-1} + x_t ;
// y = sum_n CB_n h'_n.   Measured-best structure (R4: 109.0 us):
//   pass1: E_k = G @ X_k                   G[n][s] = Abar_n^(63-s)
//   pass2: carry[k] = AbarT*carry[k-1]+E[k-1]  (serial over k, in place)
//   pass3: Y_k = T @ X_k + P @ Hc_k        T[t][s] = (t>=s) ? K[t-s] : 0
//                                          K[d] = sum_n CB_n Abar_n^d
//                                          P[t][n] = CB_n Abar_n^(t+1)
// fp32 VALU GEMMs, 4x4 register blocking. R5 falsified the MFMA variant:
// these passes are staging/traffic-bound (FLOPs/byte ~7), not compute-bound,
// so MFMA adds conversion+LDS overhead for no pipe relief.

// ---------------------------------------------------------------------------
// Pass 1: block = (chunk k, 64-ch tile). 4x4 register blocking, X & G in LDS.
// ---------------------------------------------------------------------------
__global__ __launch_bounds__(256, 4) void k_pass1(const float* __restrict__ x,
                                                  const float* __restrict__ logA,
                                                  float* __restrict__ E) {
    __shared__ float Xl[64 * 64];
    __shared__ float Gl[64 * 64];   // Gl[s][n] = Abar_n^(63-s)
    __shared__ float l2ab[64];
    int tid = threadIdx.x;
    int k   = blockIdx.x >> 3;
    int c0g = (blockIdx.x & 7) * 64;

    if (tid < 64) {
        float A = -expf(logA[tid]);
        l2ab[tid] = A * DT * LOG2E;          // log2(Abar)
    }
    const float* xsrc = x + (size_t)k * TCHUNK * CHANNELS + c0g;
    #pragma unroll
    for (int i = 0; i < 4; ++i) {
        int idx = tid + 256 * i;
        int s = idx >> 4, cq = (idx & 15) * 4;
        *(float4*)&Xl[s * 64 + cq] = *(const float4*)(xsrc + (size_t)s * CHANNELS + cq);
    }
    __syncthreads();
    {
        int s = tid >> 2, nb = (tid & 3) * 16;
        float e = (float)(63 - s);
        #pragma unroll
        for (int j = 0; j < 16; ++j) Gl[s * 64 + nb + j] = exp2f(e * l2ab[nb + j]);
    }
    __syncthreads();

    int c0 = (tid & 15) * 4;
    int n0 = (tid >> 4) * 4;
    float a00=0,a01=0,a02=0,a03=0, a10=0,a11=0,a12=0,a13=0;
    float a20=0,a21=0,a22=0,a23=0, a30=0,a31=0,a32=0,a33=0;

    #pragma unroll 8
    for (int s = 0; s < 64; ++s) {
        float4 xv = *(const float4*)&Xl[s * 64 + c0];
        float4 gv = *(const float4*)&Gl[s * 64 + n0];
        a00 = fmaf(gv.x, xv.x, a00); a01 = fmaf(gv.x, xv.y, a01);
        a02 = fmaf(gv.x, xv.z, a02); a03 = fmaf(gv.x, xv.w, a03);
        a10 = fmaf(gv.y, xv.x, a10); a11 = fmaf(gv.y, xv.y, a11);
        a12 = fmaf(gv.y, xv.z, a12); a13 = fmaf(gv.y, xv.w, a13);
        a20 = fmaf(gv.z, xv.x, a20); a21 = fmaf(gv.z, xv.y, a21);
        a22 = fmaf(gv.z, xv.z, a22); a23 = fmaf(gv.z, xv.w, a23);
        a30 = fmaf(gv.w, xv.x, a30); a31 = fmaf(gv.w, xv.y, a31);
        a32 = fmaf(gv.w, xv.z, a32); a33 = fmaf(gv.w, xv.w, a33);
    }

    float* Ep = E + ((size_t)k * NSTATE + n0) * CHANNELS + c0g + c0;
    *(float4*)(Ep)                    = make_float4(a00, a01, a02, a03);
    *(float4*)(Ep + 1 * CHANNELS)     = make_float4(a10, a11, a12, a13);
    *(float4*)(Ep + 2 * CHANNELS)     = make_float4(a20, a21, a22, a23);
    *(float4*)(Ep + 3 * CHANNELS)     = make_float4(a30, a31, a32, a33);
}

// ---------------------------------------------------------------------------
// Pass 2: per (state n, channel c): serial carry scan over chunks, in place,
// group-16 double-buffered. n is block-uniform -> aT scalar.
// ---------------------------------------------------------------------------
#define G2 16
__global__ __launch_bounds__(64, 1) void k_pass2(float* __restrict__ W,
                                                 const float* __restrict__ logA) {
    int gtid = blockIdx.x * 64 + threadIdx.x;
    int c = gtid & (CHANNELS - 1);
    int n = gtid >> 9;
    float A  = -expf(logA[n]);
    float aT = exp2f(A * (64.0f * DT) * LOG2E);   // Abar^TCHUNK
    float* p = W + (size_t)n * CHANNELS + c;
    const size_t S = (size_t)NSTATE * CHANNELS;

    float e[2][G2];
    #pragma unroll
    for (int j = 0; j < G2; ++j) e[0][j] = p[(size_t)j * S];

    float hc = 0.f;
    #pragma unroll
    for (int k0 = 0; k0 < NCHUNK; k0 += G2) {
        const int cur = (k0 / G2) & 1;
        const int nxt = cur ^ 1;
        if (k0 + G2 < NCHUNK) {
            #pragma unroll
            for (int j = 0; j < G2; ++j) e[nxt][j] = p[(size_t)(k0 + G2 + j) * S];
        }
        #pragma unroll
        for (int j = 0; j < G2; ++j) {
            p[(size_t)(k0 + j) * S] = hc;
            hc = fmaf(aT, hc, e[cur][j]);
        }
    }
}

// ---------------------------------------------------------------------------
// Pass 3: block = (chunk k, 64-ch tile). Y = T@X + P@Hc, 4x4 register blocking.
// T (Toeplitz of K), P, X, Hc all staged in LDS (~67 KB -> 2 blocks/CU).
// ---------------------------------------------------------------------------
__global__ __launch_bounds__(256, 2) void k_pass3(const float* __restrict__ x,
                                                  const float* __restrict__ logA,
                                                  const float* __restrict__ Bv,
                                                  const float* __restrict__ Cv,
                                                  const float* __restrict__ Wc,
                                                  float* __restrict__ y) {
    __shared__ float Xl[64 * 64];
    __shared__ float Hl[64 * 64];
    __shared__ float Tl[64 * 64];   // Tl[s][t] = (t>=s) ? K[t-s] : 0
    __shared__ float Pl[64 * 64];   // Pl[n][t] = CB_n * Abar_n^(t+1)
    __shared__ float l2ab[64], CBl[64], Kl[64], Kpart[4 * 64];
    int tid = threadIdx.x;
    int k   = blockIdx.x >> 3;
    int c0g = (blockIdx.x & 7) * 64;

    if (tid < 64) {
        int n = tid;
        float A    = -expf(logA[n]);
        float Bbar = expm1f(A * DT) * Bv[n] / A;
        l2ab[n] = A * DT * LOG2E;
        CBl[n]  = Cv[n] * Bbar;
    }
    const float* xsrc = x  + (size_t)k * TCHUNK * CHANNELS + c0g;
    const float* hsrc = Wc + (size_t)k * NSTATE * CHANNELS + c0g;
    #pragma unroll
    for (int i = 0; i < 4; ++i) {
        int idx = tid + 256 * i;
        int s = idx >> 4, cq = (idx & 15) * 4;
        *(float4*)&Xl[s * 64 + cq] = *(const float4*)(xsrc + (size_t)s * CHANNELS + cq);
        *(float4*)&Hl[s * 64 + cq] = *(const float4*)(hsrc + (size_t)s * CHANNELS + cq);
    }
    __syncthreads();
    {   // Pl: 16 entries per thread
        int n = tid >> 2, tb = (tid & 3) * 16;
        float l2 = l2ab[n], cb = CBl[n];
        #pragma unroll
        for (int j = 0; j < 16; ++j)
            Pl[n * 64 + tb + j] = cb * exp2f((float)(tb + j + 1) * l2);
    }
    {   // K partials: thread (d = tid&63, q = tid>>6) sums 16 states
        int d = tid & 63, q = tid >> 6;
        float s = 0.f;
        #pragma unroll
        for (int i = 0; i < 16; ++i) {
            int n = q * 16 + i;
            s = fmaf(CBl[n], exp2f((float)d * l2ab[n]), s);
        }
        Kpart[q * 64 + d] = s;
    }
    __syncthreads();
    if (tid < 64)
        Kl[tid] = (Kpart[tid] + Kpart[64 + tid]) + (Kpart[128 + tid] + Kpart[192 + tid]);
    __syncthreads();
    {   // Tl: 16 entries per thread
        int s = tid >> 2, tb = (tid & 3) * 16;
        #pragma unroll
        for (int j = 0; j < 16; ++j) {
            int t = tb + j;
            Tl[s * 64 + t] = (t >= s) ? Kl[t - s] : 0.f;
        }
    }
    __syncthreads();

    int c0 = (tid & 15) * 4;
    int t0 = (tid >> 4) * 4;
    float a00=0,a01=0,a02=0,a03=0, a10=0,a11=0,a12=0,a13=0;
    float a20=0,a21=0,a22=0,a23=0, a30=0,a31=0,a32=0,a33=0;

    #pragma unroll 4
    for (int s = 0; s < 64; ++s) {
        float4 xv = *(const float4*)&Xl[s * 64 + c0];
        float4 tv = *(const float4*)&Tl[s * 64 + t0];
        a00 = fmaf(tv.x, xv.x, a00); a01 = fmaf(tv.x, xv.y, a01);
        a02 = fmaf(tv.x, xv.z, a02); a03 = fmaf(tv.x, xv.w, a03);
        a10 = fmaf(tv.y, xv.x, a10); a11 = fmaf(tv.y, xv.y, a11);
        a12 = fmaf(tv.y, xv.z, a12); a13 = fmaf(tv.y, xv.w, a13);
        a20 = fmaf(tv.z, xv.x, a20); a21 = fmaf(tv.z, xv.y, a21);
        a22 = fmaf(tv.z, xv.z, a22); a23 = fmaf(tv.z, xv.w, a23);
        a30 = fmaf(tv.w, xv.x, a30); a31 = fmaf(tv.w, xv.y, a31);
        a32 = fmaf(tv.w, xv.z, a32); a33 = fmaf(tv.w, xv.w, a33);
    }
    #pragma unroll 4
    for (int n = 0; n < 64; ++n) {
        float4 hv = *(const float4*)&Hl[n * 64 + c0];
        float4 pv = *(const float4*)&Pl[n * 64 + t0];
        a00 = fmaf(pv.x, hv.x, a00); a01 = fmaf(pv.x, hv.y, a01);
        a02 = fmaf(pv.x, hv.z, a02); a03 = fmaf(pv.x, hv.w, a03);
        a10 = fmaf(pv.y, hv.x, a10); a11 = fmaf(pv.y, hv.y, a11);
        a12 = fmaf(pv.y, hv.z, a12); a13 = fmaf(pv.y, hv.w, a13);
        a20 = fmaf(pv.z, hv.x, a20); a21 = fmaf(pv.z, hv.y, a21);
        a22 = fmaf(pv.z, hv.z, a22); a23 = fmaf(pv.z, hv.w, a23);
        a30 = fmaf(pv.w, hv.x, a30); a31 = fmaf(pv.w, hv.y, a31);
        a32 = fmaf(pv.w, hv.z, a32); a33 = fmaf(pv.w, hv.w, a33);
    }

    float* yp = y + ((size_t)k * TCHUNK + t0) * CHANNELS + c0g + c0;
    *(float4*)(yp)                = make_float4(a00, a01, a02, a03);
    *(float4*)(yp + 1 * CHANNELS) = make_float4(a10, a11, a12, a13);
    *(float4*)(yp + 2 * CHANNELS) = make_float4(a20, a21, a22, a23);
    *(float4*)(yp + 3 * CHANNELS) = make_float4(a30, a31, a32, a33);
}

// ---------------------------------------------------------------------------
// Fallback (only if ws is too small): one thread per channel, full scan.
// ---------------------------------------------------------------------------
__global__ __launch_bounds__(256) void k_fallback(const float* __restrict__ x,
                                                  const float* __restrict__ logA,
                                                  const float* __restrict__ B,
                                                  const float* __restrict__ C,
                                                  float* __restrict__ y) {
    int c = blockIdx.x * blockDim.x + threadIdx.x;
    if (c >= CHANNELS) return;
    float Abar[NSTATE], CB[NSTATE], h[NSTATE];
    for (int n = 0; n < NSTATE; ++n) {
        float A    = -expf(logA[n]);
        float ab   = exp2f(A * DT * LOG2E);
        float Bbar = expm1f(A * DT) * B[n] / A;
        Abar[n] = ab;
        CB[n]   = C[n] * Bbar;
        h[n]    = 0.f;
    }
    for (int t = 0; t < LENGTH; ++t) {
        float xv = x[(size_t)t * CHANNELS + c];
        float acc = 0.f;
        for (int n = 0; n < NSTATE; ++n) {
            h[n] = fmaf(Abar[n], h[n], xv);
            acc  = fmaf(CB[n], h[n], acc);
        }
        y[(size_t)t * CHANNELS + c] = acc;
    }
}

extern "C" void kernel_launch(void* const* d_in, const int* in_sizes, int n_in,
                              void* d_out, int out_size, void* d_ws, size_t ws_size,
                              hipStream_t stream) {
    const float* x    = (const float*)d_in[0];
    const float* logA = (const float*)d_in[1];
    const float* B    = (const float*)d_in[2];
    const float* C    = (const float*)d_in[3];
    float* yout = (float*)d_out;

    if (ws_size < (size_t)E_ELEMS * sizeof(float)) {
        k_fallback<<<(CHANNELS + 255) / 256, 256, 0, stream>>>(x, logA, B, C, yout);
        return;
    }
    float* W = (float*)d_ws;   // E / carry buffer, 16 MB

    k_pass1<<<NCHUNK * 8, 256, 0, stream>>>(x, logA, W);
    k_pass2<<<(NSTATE * CHANNELS) / 64, 64, 0, stream>>>(W, logA);
    k_pass3<<<NCHUNK * 8, 256, 0, stream>>>(x, logA, B, C, W, yout);
}